// Round 3
// baseline (89.594 us; speedup 1.0000x reference)
//
#include <hip/hip_runtime.h>
#include <hip/hip_bf16.h>
#include <math.h>

#define B_ 256
#define D_ 512
#define C_ 100000

#define SCALE_  64.0f
#define ALPHA_  1.2f
// THRESH = cos(pi - 0.5), MM = sin(pi - 0.5) * 0.5
#define THRESH_ (-0.8775825618903728f)
#define MM_     (0.23971276930210156f)
#define COSM_   (0.8775825618903728f)   // cos(0.5)
#define SINM_   (0.4794255386042030f)   // sin(0.5)

typedef __bf16 bf16x8 __attribute__((ext_vector_type(8)));
typedef __bf16 bf16x4 __attribute__((ext_vector_type(4)));
typedef float  f32x4  __attribute__((ext_vector_type(4)));

// ---------------------------------------------------------------------------
// prep: normalize input rows -> bf16 stored in MFMA-A-frag-linear layout
// (16x32 tiles of 1 KiB; tile_idx = rowtile*16 + ktile; lane holds row
// (l&15), 8 k at (l>>4)*8). Also a_lb + canonical labels.
// grid: 256 blocks x 64 threads (1 wave per input row)
// ---------------------------------------------------------------------------
__global__ void prep_kernel(const float* __restrict__ inp,
                            const int* __restrict__ lab_raw,
                            const float* __restrict__ weight,
                            __bf16* __restrict__ xnf,
                            float* __restrict__ a_lb,
                            int* __restrict__ lab32) {
    const int b = blockIdx.x;
    const int l = threadIdx.x;   // 0..63  (covers cols l*8 .. l*8+7)

    // int64 labels (little-endian) have all-zero high words.
    const bool is64 = (lab_raw[1] == 0) & (lab_raw[3] == 0) & (lab_raw[5] == 0) &
                      (lab_raw[7] == 0) & (lab_raw[9] == 0) & (lab_raw[11] == 0) &
                      (lab_raw[13] == 0) & (lab_raw[15] == 0);
    const int lab = is64 ? lab_raw[2 * b] : lab_raw[b];

    const float* ip = inp + b * D_ + l * 8;
    f32x4 v0 = *(const f32x4*)ip;
    f32x4 v1 = *(const f32x4*)(ip + 4);
    float ss = v0.x * v0.x + v0.y * v0.y + v0.z * v0.z + v0.w * v0.w +
               v1.x * v1.x + v1.y * v1.y + v1.z * v1.z + v1.w * v1.w;
#pragma unroll
    for (int m = 1; m < 64; m <<= 1) ss += __shfl_xor(ss, m);
    const float ninv = 1.0f / fmaxf(sqrtf(ss), 1e-12f);

    float xf[8] = {v0.x * ninv, v0.y * ninv, v0.z * ninv, v0.w * ninv,
                   v1.x * ninv, v1.y * ninv, v1.z * ninv, v1.w * ninv};
    bf16x8 xv;
#pragma unroll
    for (int i = 0; i < 8; ++i) xv[i] = (__bf16)xf[i];

    const int tile_idx = (b >> 4) * 16 + (l >> 2);
    const int lf = (b & 15) + ((l & 3) << 4);
    *(bf16x8*)((char*)xnf + tile_idx * 1024 + lf * 16) = xv;

    // target-class cosine in f32
    const float* wp = weight + (size_t)lab * D_ + l * 8;
    f32x4 w0 = *(const f32x4*)wp;
    f32x4 w1 = *(const f32x4*)(wp + 4);
    float wss = w0.x * w0.x + w0.y * w0.y + w0.z * w0.z + w0.w * w0.w +
                w1.x * w1.x + w1.y * w1.y + w1.z * w1.z + w1.w * w1.w;
    float dp = xf[0] * w0.x + xf[1] * w0.y + xf[2] * w0.z + xf[3] * w0.w +
               xf[4] * w1.x + xf[5] * w1.y + xf[6] * w1.z + xf[7] * w1.w;
#pragma unroll
    for (int m = 1; m < 64; m <<= 1) {
        wss += __shfl_xor(wss, m);
        dp  += __shfl_xor(dp, m);
    }
    if (l == 0) {
        const float cos_lb = dp / fmaxf(sqrtf(wss), 1e-12f);
        const float ccl = fminf(fmaxf(cos_lb, -1.0f), 1.0f);
        const float s = sqrtf(fmaxf(0.0f, 1.0f - ccl * ccl));
        const float a1 = ccl * COSM_ - s * SINM_;   // cos(acos(c) + margin)
        a_lb[b] = (cos_lb > THRESH_) ? a1 : (cos_lb - MM_);
        lab32[b] = lab;
    }
}

// ---------------------------------------------------------------------------
// GEMM + epilogue, burst-stage structure. Block = M=256 x BN=32, 256 threads
// (4 waves; wave w computes rows w*64..+63 x all 32 cols). Phase 1: block
// burst-loads its whole 32x512 f32 W panel (64 KiB) with 1KiB/instr coalesced
// wave reads, fused sumsq, f32->bf16 into XOR-swizzled LDS. ONE barrier.
// Phase 2: barrier-free K=512 MFMA sweep, A-frags double-buffered from
// frag-linear xnf (L2-resident). Epilogue applies norms + arcface rules.
// ---------------------------------------------------------------------------
#define BN 32

__global__ __launch_bounds__(256, 3)
void gemm_kernel(const __bf16* __restrict__ xnf,
                 const float* __restrict__ weight,
                 const float* __restrict__ a_lb,
                 const int* __restrict__ lab32,
                 float* __restrict__ out) {
    __shared__ __align__(16) char wT[BN * D_ * 2];   // 32 KiB
    __shared__ float wssq[BN];

    const int tid  = threadIdx.x;
    const int lane = tid & 63;
    const int w    = tid >> 6;     // wave 0..3
    const int n0   = blockIdx.x * BN;

    f32x4 acc[4][2] = {};

    // ---- Phase 1: burst-stage W panel. Wave w owns rows w*8 .. w*8+7.
    // Iteration i (0..15): row = w*8 + (i>>1), half = i&1, lane covers 16 B.
    // Per-instruction footprint: 64 lanes x 16 B = 1 KiB contiguous.
    const float* wpanel = weight + (size_t)(n0 + w * 8) * D_;

    f32x4 wva[8], wvb[8];
#pragma unroll
    for (int i = 0; i < 8; ++i)
        wva[i] = *(const f32x4*)(wpanel + (i >> 1) * D_ + (i & 1) * 256 + lane * 4);
#pragma unroll
    for (int i = 0; i < 8; ++i)
        wvb[i] = *(const f32x4*)(wpanel + ((i + 8) >> 1) * D_ + (i & 1) * 256 + lane * 4);

    // prefetch first A-frags while W is in flight (independent of LDS)
    bf16x8 af[2][4];
#pragma unroll
    for (int m = 0; m < 4; ++m)
        af[0][m] = *(const bf16x8*)((const char*)xnf + ((w * 4 + m) * 16 + 0) * 1024 + lane * 16);

    // process chunk A then B: sumsq + cvt + swizzled ds_write
#pragma unroll
    for (int c = 0; c < 2; ++c) {
        float ss = 0.0f;
#pragma unroll
        for (int i = 0; i < 8; ++i) {
            f32x4 v = (c == 0) ? wva[i] : wvb[i];
            ss += v.x * v.x + v.y * v.y + v.z * v.z + v.w * v.w;
            bf16x4 h;
            h[0] = (__bf16)v.x; h[1] = (__bf16)v.y;
            h[2] = (__bf16)v.z; h[3] = (__bf16)v.w;
            const int row = w * 8 + c * 4 + (i >> 1);
            int off = row * (D_ * 2) + (i & 1) * 512 + lane * 8;
            off ^= (row & 7) << 4;
            *(bf16x4*)(wT + off) = h;
            if (i & 1) {   // finished a row: full-wave reduce, lane0 stores
#pragma unroll
                for (int msk = 1; msk < 64; msk <<= 1) ss += __shfl_xor(ss, msk);
                if (lane == 0) wssq[row] = ss;
                ss = 0.0f;
            }
        }
    }
    __syncthreads();   // the only barrier

    // ---- Phase 2: K sweep, 16 k-slices of 32, barrier-free.
    bf16x8 bfr[2][2];
#pragma unroll
    for (int n = 0; n < 2; ++n) {
        const int row = n * 16 + (lane & 15);
        int off = row * (D_ * 2) + 0 * 64 + (lane >> 4) * 16;
        off ^= (row & 7) << 4;
        bfr[0][n] = *(const bf16x8*)(wT + off);
    }

    for (int ks = 0; ks < 16; ++ks) {
        const int cur = ks & 1, nxt = cur ^ 1;
        if (ks < 15) {
#pragma unroll
            for (int m = 0; m < 4; ++m)
                af[nxt][m] = *(const bf16x8*)((const char*)xnf +
                             ((w * 4 + m) * 16 + ks + 1) * 1024 + lane * 16);
#pragma unroll
            for (int n = 0; n < 2; ++n) {
                const int row = n * 16 + (lane & 15);
                int off = row * (D_ * 2) + (ks + 1) * 64 + (lane >> 4) * 16;
                off ^= (row & 7) << 4;
                bfr[nxt][n] = *(const bf16x8*)(wT + off);
            }
        }
#pragma unroll
        for (int m = 0; m < 4; ++m)
#pragma unroll
            for (int n = 0; n < 2; ++n)
                acc[m][n] = __builtin_amdgcn_mfma_f32_16x16x32_bf16(
                    af[cur][m], bfr[cur][n], acc[m][n], 0, 0, 0);
    }

    // ---- Epilogue
    float al_r[16];
    int   lb_r[16];
    const int rb0 = w * 64 + ((lane >> 4) << 2);
#pragma unroll
    for (int m = 0; m < 4; ++m)
#pragma unroll
        for (int j = 0; j < 4; ++j) {
            const int b = rb0 + m * 16 + j;
            al_r[m * 4 + j] = a_lb[b];
            lb_r[m * 4 + j] = lab32[b];
        }

#pragma unroll
    for (int n = 0; n < 2; ++n) {
        const int ln = n * 16 + (lane & 15);
        const int c = n0 + ln;
        const float winv = 1.0f / fmaxf(sqrtf(wssq[ln]), 1e-12f);
#pragma unroll
        for (int m = 0; m < 4; ++m)
#pragma unroll
            for (int j = 0; j < 4; ++j) {
                const int b = rb0 + m * 16 + j;
                const float al = al_r[m * 4 + j];
                const float cosv = acc[m][n][j] * winv;
                const float d = cosv - al;
                const float t = ALPHA_ * __expf(-0.5f * d * d);  // SIGMA = 2
                const float o = (c == lb_r[m * 4 + j]) ? al : (t * cosv + t - 1.0f);
                out[(size_t)b * C_ + c] = SCALE_ * o;   // 100000 = 3125*32, no tail
            }
    }
}

extern "C" void kernel_launch(void* const* d_in, const int* in_sizes, int n_in,
                              void* d_out, int out_size, void* d_ws, size_t ws_size,
                              hipStream_t stream) {
    const float* inp = (const float*)d_in[0];
    const int*   lab = (const int*)d_in[1];
    const float* w   = (const float*)d_in[2];
    float* out = (float*)d_out;

    char* ws = (char*)d_ws;
    __bf16* xnf  = (__bf16*)ws;                       // 256*512*2 = 262144 B
    float*  a_lb = (float*)(ws + 262144);             // 1 KiB
    int*    l32  = (int*)(ws + 262144 + 1024);        // 1 KiB

    prep_kernel<<<B_, 64, 0, stream>>>(inp, lab, w, xnf, a_lb, l32);
    gemm_kernel<<<C_ / BN, 256, 0, stream>>>(xnf, w, a_lb, l32, out);
}